// Round 8
// baseline (1211.260 us; speedup 1.0000x reference)
//
#include <hip/hip_runtime.h>
#include <cstddef>
#include <cstdint>

#define HIDV 256
#define KR 64
#define NH 4
#define DHV 64

typedef float f4 __attribute__((ext_vector_type(4)));

__device__ __forceinline__ float dotf4(f4 a, f4 b) {
  return a.x*b.x + a.y*b.y + a.z*b.z + a.w*b.w;
}
__device__ __forceinline__ f4 ntload4(const float* p) {
  return __builtin_nontemporal_load(reinterpret_cast<const f4*>(p));
}
__device__ __forceinline__ void ntstore4(float* p, f4 v) {
  __builtin_nontemporal_store(v, reinterpret_cast<f4*>(p));
}

template<int CTRL>
__device__ __forceinline__ float dppadd(float v) {
  int m = __builtin_amdgcn_update_dpp(0, __float_as_int(v), CTRL, 0xf, 0xf, true);
  return v + __int_as_float(m);
}
__device__ __forceinline__ float red64f(float v) {
  v = dppadd<0xB1>(v);
  v = dppadd<0x4E>(v);
  v = dppadd<0x124>(v);
  v = dppadd<0x128>(v);
  v += __shfl_xor(v, 16);
  v += __shfl_xor(v, 32);
  return v;
}

// ---------- prep: transpose-interleave weights (byte-identical to R5) ----------
__global__ __launch_bounds__(256) void k_prep(
    const float* __restrict__ ipw, const float* __restrict__ w_ad1,
    const float* __restrict__ w_im1, const float* __restrict__ opw,
    float* __restrict__ wqT4, float* __restrict__ wkI4, float* __restrict__ ad1T4,
    float* __restrict__ im1T4, float* __restrict__ wvT4, float* __restrict__ opwT4)
{
  const int t = threadIdx.x;
  const int bid = blockIdx.x;
  const float* src; float* dst; int O, C; bool ilv = false; int idx;
  if (bid < 64)       { src = ipw;          dst = wqT4;  O = 256; C = 256; idx = bid*256 + t; }
  else if (bid < 128) { src = ipw + 65536;  dst = wkI4;  O = 256; C = 256; idx = (bid-64)*256 + t; ilv = true; }
  else if (bid < 160) { src = w_ad1;        dst = ad1T4; O = 128; C = 256; idx = (bid-128)*256 + t; }
  else if (bid < 288) { src = w_im1;        dst = im1T4; O = 256; C = 512; idx = (bid-160)*256 + t; }
  else if (bid < 352) { src = ipw + 131072; dst = wvT4;  O = 256; C = 256; idx = (bid-288)*256 + t; }
  else                { src = opw;          dst = opwT4; O = 256; C = 256; idx = (bid-352)*256 + t; }
  if (idx >= O*(C/4)) return;
  f4 v;
  if (!ilv) {
    int o = idx % O, c4 = idx / O;
    const float* s = src + (size_t)o*C + 4*c4;
    v.x = s[0]; v.y = s[1]; v.z = s[2]; v.w = s[3];
    reinterpret_cast<f4*>(dst)[(size_t)c4*O + o] = v;
  } else {
    int c = idx & 255, d4 = idx >> 8;
    v.x = src[(size_t)(4*d4+0)*256 + c];
    v.y = src[(size_t)(4*d4+1)*256 + c];
    v.z = src[(size_t)(4*d4+2)*256 + c];
    v.w = src[(size_t)(4*d4+3)*256 + c];
    reinterpret_cast<f4*>(dst)[(size_t)d4*256 + c] = v;
  }
}

// ---------------- K0: R5 body, REP-wrapped for counter capture ----------------
__global__ __launch_bounds__(256) void k0_mlp_qk(
    const float* __restrict__ msg, const float* __restrict__ ipb,
    const float* __restrict__ b_ad1, const float* __restrict__ w_ad2,
    const float* __restrict__ b_ad2,
    const float* __restrict__ wqT4, const float* __restrict__ wkI4,
    const float* __restrict__ ad1T4,
    float* __restrict__ qk_ws, float* __restrict__ la_ws, int B, int REP)
{
  __shared__ float q_s[8][HIDV];
  __shared__ float redw[4][8];
  const int t = threadIdx.x, lane = t & 63, wvi = t >> 6;
  const f4* wq4 = reinterpret_cast<const f4*>(wqT4);
  const f4* wk4 = reinterpret_cast<const f4*>(wkI4);
  const f4* a14 = reinterpret_cast<const f4*>(ad1T4);

  for (int rep = 0; rep < REP; ++rep) {
    int b0 = blockIdx.x * 8;
    asm volatile("" : "+s"(b0));          // prevent cross-rep hoisting
    int w_off = 0;
    asm volatile("" : "+s"(w_off));
    __syncthreads();

    int brc[8];
    #pragma unroll
    for (int r = 0; r < 8; ++r) { int b = b0 + r; brc[r] = (b < B) ? b : B-1; }

    {
      float acc[8];
      float bq = ipb[t];
      #pragma unroll
      for (int r = 0; r < 8; ++r) acc[r] = bq;
      #pragma unroll 2
      for (int c4 = 0; c4 < 64; ++c4) {
        f4 w = wq4[c4*256 + t + w_off];
        #pragma unroll
        for (int r = 0; r < 8; ++r) {
          f4 m = *reinterpret_cast<const f4*>(msg + (size_t)brc[r]*HIDV + c4*4);
          acc[r] += dotf4(w, m);
        }
      }
      #pragma unroll
      for (int r = 0; r < 8; ++r) q_s[r][t] = acc[r];
    }
    __syncthreads();

    for (int h = 0; h < NH; ++h) {
      float a2[8];
      #pragma unroll
      for (int r = 0; r < 8; ++r) a2[r] = 0.f;
      #pragma unroll 2
      for (int d4 = 0; d4 < 16; ++d4) {
        f4 w = wk4[(h*16 + d4)*256 + t + w_off];
        #pragma unroll
        for (int r = 0; r < 8; ++r) {
          f4 q4 = *reinterpret_cast<const f4*>(&q_s[r][h*64 + d4*4]);
          a2[r] += dotf4(w, q4);
        }
      }
      #pragma unroll
      for (int r = 0; r < 8; ++r) {
        int b = b0 + r;
        if (b < B) qk_ws[(size_t)b*(NH*HIDV) + h*HIDV + t] = a2[r];
      }
    }

    {
      float prod[8];
      if (t < 128) {
        float h1[8];
        float bb = b_ad1[t];
        #pragma unroll
        for (int r = 0; r < 8; ++r) h1[r] = bb;
        #pragma unroll 2
        for (int c4 = 0; c4 < 64; ++c4) {
          f4 w = a14[c4*128 + t + w_off];
          #pragma unroll
          for (int r = 0; r < 8; ++r) {
            f4 m = *reinterpret_cast<const f4*>(msg + (size_t)brc[r]*HIDV + c4*4);
            h1[r] += dotf4(w, m);
          }
        }
        float wa2 = w_ad2[t];
        #pragma unroll
        for (int r = 0; r < 8; ++r) prod[r] = fmaxf(h1[r], 0.f) * wa2;
      } else {
        #pragma unroll
        for (int r = 0; r < 8; ++r) prod[r] = 0.f;
      }
      #pragma unroll
      for (int r = 0; r < 8; ++r) prod[r] = red64f(prod[r]);
      if (lane == 0) {
        #pragma unroll
        for (int r = 0; r < 8; ++r) redw[wvi][r] = prod[r];
      }
      __syncthreads();
      if (t < 8) {
        int b = b0 + t;
        if (b < B) {
          float x = redw[0][t] + redw[1][t] + redw[2][t] + redw[3][t] + b_ad2[0];
          la_ws[b] = 1.f / (1.f + expf(-x));
        }
      }
    }
  }
}

// ---------------- K1: R5 body, REP-wrapped ----------------
__global__ __launch_bounds__(256) void k1_stream(
    const float* __restrict__ storage, const float* __restrict__ msg,
    const float* __restrict__ qk_ws,
    float* __restrict__ upd,
    float* __restrict__ mean_ws, float* __restrict__ pv_ws,
    float* __restrict__ se_ws, float* __restrict__ s0c_ws,
    float* __restrict__ stat_ws, int B, int REP)
{
  const int t = threadIdx.x, lane = t & 63, wv = t >> 6;
  const int c0 = lane * 4;

  for (int rep = 0; rep < REP; ++rep) {
    int bb = blockIdx.x * 4 + wv;
    asm volatile("" : "+v"(bb));          // prevent cross-rep hoisting
    if (bb < B) {
      const int b = bb;
      const float* __restrict__ srow = storage + (size_t)b*KR*HIDV;
      float* __restrict__ urow = upd + (size_t)b*KR*HIDV;
      const float* __restrict__ qkp = qk_ws + (size_t)b*(NH*HIDV);

      const f4 qk0 = *reinterpret_cast<const f4*>(qkp + 0*HIDV + c0);
      const f4 qk1 = *reinterpret_cast<const f4*>(qkp + 1*HIDV + c0);
      const f4 qk2 = *reinterpret_cast<const f4*>(qkp + 2*HIDV + c0);
      const f4 qk3 = *reinterpret_cast<const f4*>(qkp + 3*HIDV + c0);
      const f4 msgr = *reinterpret_cast<const f4*>(msg + (size_t)b*HIDV + c0);

      {
        float a0 = red64f(dotf4(qk0, msgr));
        float a1 = red64f(dotf4(qk1, msgr));
        float a2 = red64f(dotf4(qk2, msgr));
        float a3 = red64f(dotf4(qk3, msgr));
        if (lane == 0) {
          s0c_ws[(size_t)b*NH + 0] = a0;
          s0c_ws[(size_t)b*NH + 1] = a1;
          s0c_ws[(size_t)b*NH + 2] = a2;
          s0c_ws[(size_t)b*NH + 3] = a3;
        }
      }

      f4 S1 = {0.f,0.f,0.f,0.f}, S2 = {0.f,0.f,0.f,0.f};
      f4 pv0 = {0.f,0.f,0.f,0.f}, pv1 = {0.f,0.f,0.f,0.f};
      f4 pv2 = {0.f,0.f,0.f,0.f}, pv3 = {0.f,0.f,0.f,0.f};
      float se0 = 0.f, se1 = 0.f, se2 = 0.f, se3 = 0.f;
      float cntf = 0.f;
      float dw = 1.f;

      f4 x[4], xn[4];
      #pragma unroll
      for (int rr = 0; rr < 4; ++rr)
        x[rr] = ntload4(srow + (size_t)rr*HIDV + c0);

      for (int g = 0; g < 16; ++g) {
        const int j0 = g*4;
        if (g < 15) {
          #pragma unroll
          for (int rr = 0; rr < 4; ++rr)
            xn[rr] = ntload4(srow + (size_t)(j0+4+rr)*HIDV + c0);
        }
        #pragma unroll
        for (int rr = 0; rr < 4; ++rr) {
          const int j = j0 + rr;
          f4 xx = x[rr];
          unsigned long long bal = __ballot(xx.x != 0.f || xx.y != 0.f ||
                                            xx.z != 0.f || xx.w != 0.f);
          if (bal) {
            cntf += 1.f;
            S1 += xx;
            S2 += xx*xx;
          }
          float sp0 = dotf4(qk0, xx);
          float sp1 = dotf4(qk1, xx);
          float sp2 = dotf4(qk2, xx);
          float sp3 = dotf4(qk3, xx);
          sp0 = red64f(sp0); sp1 = red64f(sp1);
          sp2 = red64f(sp2); sp3 = red64f(sp3);
          if (j < KR-1) {
            f4 u = xx * dw;
            ntstore4(urow + (size_t)(j+1)*HIDV + c0, u);
            float f = dw * 0.125f;
            float e0 = __expf(sp0*f), e1 = __expf(sp1*f);
            float e2 = __expf(sp2*f), e3 = __expf(sp3*f);
            se0 += e0; se1 += e1; se2 += e2; se3 += e3;
            pv0 += xx * (e0*dw); pv1 += xx * (e1*dw);
            pv2 += xx * (e2*dw); pv3 += xx * (e3*dw);
          }
          dw *= 0.95f;
        }
        if (g < 15) {
          #pragma unroll
          for (int rr = 0; rr < 4; ++rr) x[rr] = xn[rr];
        }
      }

      const float msum = cntf + 1e-8f;
      const float inv = 1.f / msum;
      f4 mn;
      mn.x = S1.x*inv; mn.y = S1.y*inv; mn.z = S1.z*inv; mn.w = S1.w*inv;
      *reinterpret_cast<f4*>(mean_ws + (size_t)b*HIDV + c0) = mn;

      float ind = 0.f;
      {
        float vx = S2.x - 2.f*mn.x*S1.x + mn.x*mn.x*cntf;
        float vy = S2.y - 2.f*mn.y*S1.y + mn.y*mn.y*cntf;
        float vz = S2.z - 2.f*mn.z*S1.z + mn.z*mn.z*cntf;
        float vw = S2.w - 2.f*mn.w*S1.w + mn.w*mn.w*cntf;
        float sx = sqrtf(fmaxf(vx,0.f)*inv), sy = sqrtf(fmaxf(vy,0.f)*inv);
        float sz = sqrtf(fmaxf(vz,0.f)*inv), sw = sqrtf(fmaxf(vw,0.f)*inv);
        ind += (fabsf((msgr.x-mn.x)/(sx+1e-8f)) > 2.f) ? 1.f : 0.f;
        ind += (fabsf((msgr.y-mn.y)/(sy+1e-8f)) > 2.f) ? 1.f : 0.f;
        ind += (fabsf((msgr.z-mn.z)/(sz+1e-8f)) > 2.f) ? 1.f : 0.f;
        ind += (fabsf((msgr.w-mn.w)/(sw+1e-8f)) > 2.f) ? 1.f : 0.f;
      }
      ind = red64f(ind);

      float* pvp = pv_ws + (size_t)b*(NH*HIDV);
      *reinterpret_cast<f4*>(pvp + 0*HIDV + c0) = pv0;
      *reinterpret_cast<f4*>(pvp + 1*HIDV + c0) = pv1;
      *reinterpret_cast<f4*>(pvp + 2*HIDV + c0) = pv2;
      *reinterpret_cast<f4*>(pvp + 3*HIDV + c0) = pv3;

      if (lane == 0) {
        se_ws[(size_t)b*NH + 0] = se0;
        se_ws[(size_t)b*NH + 1] = se1;
        se_ws[(size_t)b*NH + 2] = se2;
        se_ws[(size_t)b*NH + 3] = se3;
        stat_ws[b] = ind * (1.f/256.f);
      }
    }
  }
}

// ---------------- K3: R5 body, REP-wrapped ----------------
__global__ __launch_bounds__(256) void k3_out(
    const float* __restrict__ msg, const float* __restrict__ mean_ws,
    const float* __restrict__ pv_ws, const float* __restrict__ se_ws,
    const float* __restrict__ s0c_ws, const float* __restrict__ stat_ws,
    const float* __restrict__ la_ws, const float* __restrict__ b_im1,
    const float* __restrict__ w_im2, const float* __restrict__ b_im2,
    const float* __restrict__ ipb, const float* __restrict__ opb,
    const float* __restrict__ im1T4, const float* __restrict__ wvT4,
    const float* __restrict__ opwT4,
    float* __restrict__ pu_ws, float* __restrict__ upd, float* __restrict__ agg,
    int B, int REP)
{
  __shared__ float g_s[8][HIDV];
  __shared__ float ctx_s[8][HIDV];
  __shared__ float imp_s[8];
  const int t = threadIdx.x;
  const f4* w14 = reinterpret_cast<const f4*>(im1T4);
  const f4* wv4 = reinterpret_cast<const f4*>(wvT4);
  const f4* op4 = reinterpret_cast<const f4*>(opwT4);

  for (int rep = 0; rep < REP; ++rep) {
    int b0 = blockIdx.x * 8;
    asm volatile("" : "+s"(b0));
    int w_off = 0;
    asm volatile("" : "+s"(w_off));
    __syncthreads();

    int brc[8];
    #pragma unroll
    for (int r = 0; r < 8; ++r) { int b = b0 + r; brc[r] = (b < B) ? b : B-1; }

    {
      float acc[8];
      float bi = b_im1[t];
      #pragma unroll
      for (int r = 0; r < 8; ++r) acc[r] = bi;
      #pragma unroll 2
      for (int c4 = 0; c4 < 64; ++c4) {
        f4 w = w14[c4*256 + t + w_off];
        #pragma unroll
        for (int r = 0; r < 8; ++r) {
          f4 m = *reinterpret_cast<const f4*>(msg + (size_t)brc[r]*HIDV + c4*4);
          acc[r] += dotf4(w, m);
        }
      }
      #pragma unroll 2
      for (int c4 = 64; c4 < 128; ++c4) {
        f4 w = w14[c4*256 + t + w_off];
        #pragma unroll
        for (int r = 0; r < 8; ++r) {
          f4 m = *reinterpret_cast<const f4*>(mean_ws + (size_t)brc[r]*HIDV + (c4-64)*4);
          acc[r] += dotf4(w, m);
        }
      }
      #pragma unroll
      for (int r = 0; r < 8; ++r) g_s[r][t] = fmaxf(acc[r], 0.f);
    }
    __syncthreads();

    {
      int rg = t >> 5, li = t & 31;
      f4 ga = *reinterpret_cast<const f4*>(&g_s[rg][li*8]);
      f4 gb = *reinterpret_cast<const f4*>(&g_s[rg][li*8 + 4]);
      f4 wa = *reinterpret_cast<const f4*>(&w_im2[li*8]);
      f4 wb = *reinterpret_cast<const f4*>(&w_im2[li*8 + 4]);
      float p = dotf4(ga, wa) + dotf4(gb, wb);
      p = dppadd<0xB1>(p); p = dppadd<0x4E>(p);
      p = dppadd<0x124>(p); p = dppadd<0x128>(p);
      p += __shfl_xor(p, 16);
      if (li == 0) {
        int b = b0 + rg;
        float x = p + b_im2[0];
        float sp = fmaxf(x, 0.f) + log1pf(expf(-fabsf(x)));
        float an = (b < B) ? (0.5f*stat_ws[b] + 0.5f*la_ws[b]) : 0.f;
        imp_s[rg] = sp * (1.f + an);
      }
    }
    __syncthreads();

    #pragma unroll
    for (int r = 0; r < 8; ++r) {
      int b = b0 + r;
      float msgv = msg[(size_t)brc[r]*HIDV + t];
      float impr = imp_s[r];
      if (b < B) upd[(size_t)b*KR*HIDV + t] = msgv * impr;
      #pragma unroll
      for (int h = 0; h < NH; ++h) {
        float s0 = impr * s0c_ws[(size_t)brc[r]*NH + h] * 0.125f;
        float e0 = __expf(s0);
        float invd = 1.f / (e0 + se_ws[(size_t)brc[r]*NH + h]);
        float a0 = e0 * invd;
        float val = a0*impr*msgv + pv_ws[(size_t)brc[r]*(NH*HIDV) + h*HIDV + t]*invd;
        if (b < B) pu_ws[(size_t)b*(NH*HIDV) + h*HIDV + t] = val;
      }
    }
    __syncthreads();

    {
      const int hh = t >> 6;
      float a2[8];
      float bv = ipb[2*HIDV + t];
      #pragma unroll
      for (int r = 0; r < 8; ++r) a2[r] = bv;
      #pragma unroll 2
      for (int c4 = 0; c4 < 64; ++c4) {
        f4 w = wv4[c4*256 + t + w_off];
        #pragma unroll
        for (int r = 0; r < 8; ++r) {
          f4 p4 = *reinterpret_cast<const f4*>(pu_ws + (size_t)brc[r]*(NH*HIDV) + hh*HIDV + c4*4);
          a2[r] += dotf4(w, p4);
        }
      }
      #pragma unroll
      for (int r = 0; r < 8; ++r) ctx_s[r][t] = a2[r];
    }
    __syncthreads();

    {
      float a3[8];
      float bo = opb[t];
      #pragma unroll
      for (int r = 0; r < 8; ++r) a3[r] = bo;
      #pragma unroll 2
      for (int c4 = 0; c4 < 64; ++c4) {
        f4 w = op4[c4*256 + t + w_off];
        #pragma unroll
        for (int r = 0; r < 8; ++r) {
          f4 c = *reinterpret_cast<const f4*>(&ctx_s[r][c4*4]);
          a3[r] += dotf4(w, c);
        }
      }
      #pragma unroll
      for (int r = 0; r < 8; ++r) {
        int b = b0 + r;
        if (b < B) agg[(size_t)b*HIDV + t] = a3[r];
      }
    }
  }
}

extern "C" void kernel_launch(void* const* d_in, const int* in_sizes, int n_in,
                              void* d_out, int out_size, void* d_ws, size_t ws_size,
                              hipStream_t stream) {
  const float* storage = (const float*)d_in[0];
  const float* msg     = (const float*)d_in[1];
  const float* w_ad1   = (const float*)d_in[2];
  const float* b_ad1   = (const float*)d_in[3];
  const float* w_ad2   = (const float*)d_in[4];
  const float* b_ad2   = (const float*)d_in[5];
  const float* w_im1   = (const float*)d_in[6];
  const float* b_im1   = (const float*)d_in[7];
  const float* w_im2   = (const float*)d_in[8];
  const float* b_im2   = (const float*)d_in[9];
  const float* ipw     = (const float*)d_in[10];
  const float* ipb     = (const float*)d_in[11];
  const float* opw     = (const float*)d_in[12];
  const float* opb     = (const float*)d_in[13];

  const int B = in_sizes[1] / HIDV;
  float* upd = (float*)d_out;
  float* agg = upd + (size_t)B*KR*HIDV;

  float* wsf = (float*)d_ws;
  size_t off = 0;
  float* qk    = wsf + off; off += (size_t)B*NH*HIDV;
  float* pv1   = wsf + off; off += (size_t)B*NH*HIDV;
  float* pu    = wsf + off; off += (size_t)B*NH*HIDV;
  float* mean  = wsf + off; off += (size_t)B*HIDV;
  float* se1   = wsf + off; off += (size_t)B*NH;
  float* s0c   = wsf + off; off += (size_t)B*NH;
  float* stat  = wsf + off; off += (size_t)B;
  float* la    = wsf + off; off += (size_t)B;
  float* wqT4  = wsf + off; off += 65536;
  float* wkI4  = wsf + off; off += 65536;
  float* ad1T4 = wsf + off; off += 32768;
  float* im1T4 = wsf + off; off += 131072;
  float* wvT4  = wsf + off; off += 65536;
  float* opwT4 = wsf + off; off += 65536;

  hipLaunchKernelGGL(k_prep, dim3(416), dim3(256), 0, stream,
                     ipw, w_ad1, w_im1, opw,
                     wqT4, wkI4, ad1T4, im1T4, wvT4, opwT4);
  // COUNTER-CAPTURE ROUND: in-kernel reps push each dispatch above the ~340us
  // harness fills so all three kernels land in the top-5 WITH counter rows.
  hipLaunchKernelGGL(k0_mlp_qk, dim3((B+7)/8), dim3(256), 0, stream,
                     msg, ipb, b_ad1, w_ad2, b_ad2,
                     wqT4, wkI4, ad1T4, qk, la, B, 4);
  hipLaunchKernelGGL(k1_stream, dim3((B+3)/4), dim3(256), 0, stream,
                     storage, msg, qk, upd, mean, pv1, se1, s0c, stat, B, 2);
  hipLaunchKernelGGL(k3_out, dim3((B+7)/8), dim3(256), 0, stream,
                     msg, mean, pv1, se1, s0c, stat, la,
                     b_im1, w_im2, b_im2, ipb, opb,
                     im1T4, wvT4, opwT4,
                     pu, upd, agg, B, 3);
}

// Round 9
// 282.638 us; speedup vs baseline: 4.2856x; 4.2856x over previous
//
#include <hip/hip_runtime.h>
#include <cstddef>
#include <cstdint>

#define HIDV 256
#define KR 64
#define NH 4

typedef float f4 __attribute__((ext_vector_type(4)));
typedef short bh8 __attribute__((ext_vector_type(8)));   // 8 bf16 (raw bits)
typedef unsigned int u32;

#define MFMA16(a,b,c) __builtin_amdgcn_mfma_f32_16x16x32_bf16(a,b,c,0,0,0)

__device__ __forceinline__ float dotf4(f4 a, f4 b) {
  return a.x*b.x + a.y*b.y + a.z*b.z + a.w*b.w;
}
__device__ __forceinline__ f4 ntload4(const float* p) {
  return __builtin_nontemporal_load(reinterpret_cast<const f4*>(p));
}
__device__ __forceinline__ void ntstore4(float* p, f4 v) {
  __builtin_nontemporal_store(v, reinterpret_cast<f4*>(p));
}
template<int CTRL>
__device__ __forceinline__ float dppadd(float v) {
  int m = __builtin_amdgcn_update_dpp(0, __float_as_int(v), CTRL, 0xf, 0xf, true);
  return v + __int_as_float(m);
}
__device__ __forceinline__ float red64f(float v) {
  v = dppadd<0xB1>(v);
  v = dppadd<0x4E>(v);
  v = dppadd<0x124>(v);
  v = dppadd<0x128>(v);
  v += __shfl_xor(v, 16);
  v += __shfl_xor(v, 32);
  return v;
}
// pack two f32 -> one dword of 2 bf16 (RNE), src0 in low half
__device__ __forceinline__ u32 pk2(float a, float b) {
  u32 r;
  asm("v_cvt_pk_bf16_f32 %0, %1, %2" : "=v"(r) : "v"(a), "v"(b));
  return r;
}
__device__ __forceinline__ bh8 cvt8(f4 lo, f4 hi) {
  union { bh8 b; u32 u[4]; } r;
  r.u[0] = pk2(lo.x, lo.y); r.u[1] = pk2(lo.z, lo.w);
  r.u[2] = pk2(hi.x, hi.y); r.u[3] = pk2(hi.z, hi.w);
  return r.b;
}

// ---------- prep: pack weights into MFMA B-fragment-linear bf16 ----------
// B-frag for 16x16x32: lane l holds B[k=(l>>4)*8+j][col=(l&15)] of a 32(K)x16(N) tile.
// Storage: frag[g][l][8] with g = local (ntile,kstep) group index.
__global__ __launch_bounds__(256) void k_prep_w(
    const float* __restrict__ ipw, const float* __restrict__ w_ad1,
    const float* __restrict__ w_im1, const float* __restrict__ opw,
    unsigned short* __restrict__ WQF, unsigned short* __restrict__ WKF,
    unsigned short* __restrict__ AD1F, unsigned short* __restrict__ IM1F,
    unsigned short* __restrict__ WVF, unsigned short* __restrict__ OPF)
{
  int f = blockIdx.x*256 + threadIdx.x;
  if (f >= 53248) return;
  const int l = f & 63, lr = l & 15, lk = l >> 4;
  int g = f >> 6;
  const float* src; unsigned short* dst; int stride; int gl;
  if (g < 128) {            // WQF: B[k=c][n=t] = ipw[t*256+c]; nt16 x S8
    gl = g; int nt = g >> 3, s = g & 7;
    src = ipw + (size_t)(nt*16+lr)*256 + s*32 + lk*8; stride = 1; dst = WQF;
  } else if (g < 256) {     // WKF: B_h[k=d][n=c] = ipw[65536+(h*64+d)*256+c]; (4h*16nt) x S2
    gl = g - 128; int ntg = gl >> 1, s = gl & 1; int h = ntg >> 4, ntl = ntg & 15;
    src = ipw + 65536 + (size_t)(h*64 + s*32 + lk*8)*256 + ntl*16 + lr; stride = 256; dst = WKF;
  } else if (g < 320) {     // AD1F: B[k=c][n=o] = w_ad1[o*256+c]; nt8 x S8
    gl = g - 256; int nt = gl >> 3, s = gl & 7;
    src = w_ad1 + (size_t)(nt*16+lr)*256 + s*32 + lk*8; stride = 1; dst = AD1F;
  } else if (g < 576) {     // IM1F: B[k=c][n=o] = w_im1[o*512+c]; nt16 x S16
    gl = g - 320; int nt = gl >> 4, s = gl & 15;
    src = w_im1 + (size_t)(nt*16+lr)*512 + s*32 + lk*8; stride = 1; dst = IM1F;
  } else if (g < 704) {     // WVF: B[k=c][n=t] = ipw[131072+t*256+c]; nt16 x S8
    gl = g - 576; int nt = gl >> 3, s = gl & 7;
    src = ipw + 131072 + (size_t)(nt*16+lr)*256 + s*32 + lk*8; stride = 1; dst = WVF;
  } else {                  // OPF: B[k=c][n=t] = opw[t*256+c]; nt16 x S8
    gl = g - 704; int nt = gl >> 3, s = gl & 7;
    src = opw + (size_t)(nt*16+lr)*256 + s*32 + lk*8; stride = 1; dst = OPF;
  }
  float v[8];
  #pragma unroll
  for (int j = 0; j < 8; ++j) v[j] = src[(size_t)j*stride];
  union { bh8 b; u32 u[4]; } r;
  r.u[0] = pk2(v[0], v[1]); r.u[1] = pk2(v[2], v[3]);
  r.u[2] = pk2(v[4], v[5]); r.u[3] = pk2(v[6], v[7]);
  *reinterpret_cast<bh8*>(dst + ((size_t)gl*64 + l)*8) = r.b;
}

// ---------- prep: msg fp32 -> bf16 ----------
__global__ __launch_bounds__(256) void k_prep_msg(
    const float* __restrict__ msg, unsigned short* __restrict__ msgb, int n8)
{
  int i = blockIdx.x*256 + threadIdx.x;
  if (i >= n8) return;
  const float* p = msg + (size_t)i*8;
  f4 lo = *reinterpret_cast<const f4*>(p);
  f4 hi = *reinterpret_cast<const f4*>(p+4);
  union { bh8 b; u32 u[4]; } r;
  r.u[0] = pk2(lo.x, lo.y); r.u[1] = pk2(lo.z, lo.w);
  r.u[2] = pk2(hi.x, hi.y); r.u[3] = pk2(hi.z, hi.w);
  *reinterpret_cast<bh8*>(msgb + (size_t)i*8) = r.b;
}

// ---------------- K0 (MFMA): q, qk, learned anomaly ----------------
// M=16 rows/block, 4 waves; wave w owns output cols [w*64, w*64+64).
__global__ __launch_bounds__(256) void k0_mfma(
    const unsigned short* __restrict__ msgb,
    const float* __restrict__ ipb, const float* __restrict__ b_ad1,
    const float* __restrict__ w_ad2, const float* __restrict__ b_ad2,
    const unsigned short* __restrict__ WQF, const unsigned short* __restrict__ WKF,
    const unsigned short* __restrict__ AD1F,
    float* __restrict__ qk_ws, float* __restrict__ la_ws, int B)
{
  __shared__ float q_lds[16][260];
  __shared__ float part_ad[4][16];
  const int t = threadIdx.x, l = t & 63, w = t >> 6;
  const int lr = l & 15, lk = l >> 4;
  const int b0 = blockIdx.x * 16;

  // A fragments: lane l holds A[row=lr][k=lk*8+j] per kstep
  const unsigned short* arow = msgb + (size_t)(b0 + lr) * HIDV;
  bh8 aM[8];
  #pragma unroll
  for (int s = 0; s < 8; ++s)
    aM[s] = *reinterpret_cast<const bh8*>(arow + s*32 + lk*8);

  // q GEMM (K=256, N: 4 ntiles)
  f4 qa[4];
  #pragma unroll
  for (int n = 0; n < 4; ++n) {
    float bq = ipb[w*64 + n*16 + lr];
    f4 v = {bq, bq, bq, bq};
    qa[n] = v;
  }
  #pragma unroll
  for (int s = 0; s < 8; ++s) {
    #pragma unroll
    for (int n = 0; n < 4; ++n) {
      bh8 bw = *reinterpret_cast<const bh8*>(WQF + (((size_t)(w*4+n)*8 + s)*64 + l)*8);
      qa[n] = MFMA16(aM[s], bw, qa[n]);
    }
  }

  // ad1 GEMM (N=128: ntiles w*2+{0,1})
  f4 ha[2];
  #pragma unroll
  for (int n = 0; n < 2; ++n) {
    float bb = b_ad1[w*32 + n*16 + lr];
    f4 v = {bb, bb, bb, bb};
    ha[n] = v;
  }
  #pragma unroll
  for (int s = 0; s < 8; ++s) {
    #pragma unroll
    for (int n = 0; n < 2; ++n) {
      bh8 bw = *reinterpret_cast<const bh8*>(AD1F + (((size_t)(w*2+n)*8 + s)*64 + l)*8);
      ha[n] = MFMA16(aM[s], bw, ha[n]);
    }
  }

  // q C-frags -> LDS f32 (row = lk*4+qq, col = w*64+n*16+lr)
  #pragma unroll
  for (int n = 0; n < 4; ++n)
    #pragma unroll
    for (int qq = 0; qq < 4; ++qq)
      q_lds[lk*4+qq][w*64 + n*16 + lr] = qa[n][qq];

  // ad1 epilogue: relu * wa2, sum over cols
  {
    float wa0 = w_ad2[w*32 + lr];
    float wa1 = w_ad2[w*32 + 16 + lr];
    float vv[4];
    #pragma unroll
    for (int qq = 0; qq < 4; ++qq)
      vv[qq] = fmaxf(ha[0][qq], 0.f)*wa0 + fmaxf(ha[1][qq], 0.f)*wa1;
    #pragma unroll
    for (int m = 1; m < 16; m <<= 1) {
      #pragma unroll
      for (int qq = 0; qq < 4; ++qq) vv[qq] += __shfl_xor(vv[qq], m, 64);
    }
    if (lr == 0) {
      #pragma unroll
      for (int qq = 0; qq < 4; ++qq) part_ad[w][lk*4+qq] = vv[qq];
    }
  }
  __syncthreads();
  if (t < 16) {
    float x = part_ad[0][t]+part_ad[1][t]+part_ad[2][t]+part_ad[3][t] + b_ad2[0];
    la_ws[b0 + t] = 1.f / (1.f + expf(-x));
  }

  // qk GEMM: A = q (bf16 from LDS), B = WKF per head (K=64)
  const float* qrow = &q_lds[lr][0];
  for (int h = 0; h < NH; ++h) {
    f4 ka[4];
    #pragma unroll
    for (int n = 0; n < 4; ++n) { f4 z = {0.f,0.f,0.f,0.f}; ka[n] = z; }
    #pragma unroll
    for (int s2 = 0; s2 < 2; ++s2) {
      int k0 = h*64 + s2*32 + lk*8;
      f4 lo = *reinterpret_cast<const f4*>(qrow + k0);
      f4 hi = *reinterpret_cast<const f4*>(qrow + k0 + 4);
      bh8 aQ = cvt8(lo, hi);
      #pragma unroll
      for (int n = 0; n < 4; ++n) {
        bh8 bw = *reinterpret_cast<const bh8*>(WKF + (((size_t)((h*16 + w*4+n)*2 + s2))*64 + l)*8);
        ka[n] = MFMA16(aQ, bw, ka[n]);
      }
    }
    #pragma unroll
    for (int n = 0; n < 4; ++n)
      #pragma unroll
      for (int qq = 0; qq < 4; ++qq)
        qk_ws[(size_t)(b0 + lk*4 + qq)*(NH*HIDV) + h*HIDV + w*64 + n*16 + lr] = ka[n][qq];
  }
}

// ---------------- K1: one wave per b (byte-identical to R3/R5) ----------------
__global__ __launch_bounds__(256) void k1_stream(
    const float* __restrict__ storage, const float* __restrict__ msg,
    const float* __restrict__ qk_ws,
    float* __restrict__ upd,
    float* __restrict__ mean_ws, float* __restrict__ pv_ws,
    float* __restrict__ se_ws, float* __restrict__ s0c_ws,
    float* __restrict__ stat_ws, int B)
{
  const int t = threadIdx.x, lane = t & 63, wv = t >> 6;
  const int b = blockIdx.x * 4 + wv;
  if (b >= B) return;
  const int c0 = lane * 4;

  const float* __restrict__ srow = storage + (size_t)b*KR*HIDV;
  float* __restrict__ urow = upd + (size_t)b*KR*HIDV;
  const float* __restrict__ qkp = qk_ws + (size_t)b*(NH*HIDV);

  const f4 qk0 = *reinterpret_cast<const f4*>(qkp + 0*HIDV + c0);
  const f4 qk1 = *reinterpret_cast<const f4*>(qkp + 1*HIDV + c0);
  const f4 qk2 = *reinterpret_cast<const f4*>(qkp + 2*HIDV + c0);
  const f4 qk3 = *reinterpret_cast<const f4*>(qkp + 3*HIDV + c0);
  const f4 msgr = *reinterpret_cast<const f4*>(msg + (size_t)b*HIDV + c0);

  {
    float a0 = red64f(dotf4(qk0, msgr));
    float a1 = red64f(dotf4(qk1, msgr));
    float a2 = red64f(dotf4(qk2, msgr));
    float a3 = red64f(dotf4(qk3, msgr));
    if (lane == 0) {
      s0c_ws[(size_t)b*NH + 0] = a0;
      s0c_ws[(size_t)b*NH + 1] = a1;
      s0c_ws[(size_t)b*NH + 2] = a2;
      s0c_ws[(size_t)b*NH + 3] = a3;
    }
  }

  f4 S1 = {0.f,0.f,0.f,0.f}, S2 = {0.f,0.f,0.f,0.f};
  f4 pv0 = {0.f,0.f,0.f,0.f}, pv1 = {0.f,0.f,0.f,0.f};
  f4 pv2 = {0.f,0.f,0.f,0.f}, pv3 = {0.f,0.f,0.f,0.f};
  float se0 = 0.f, se1 = 0.f, se2 = 0.f, se3 = 0.f;
  float cntf = 0.f;
  float dw = 1.f;

  f4 x[4], xn[4];
  #pragma unroll
  for (int rr = 0; rr < 4; ++rr)
    x[rr] = ntload4(srow + (size_t)rr*HIDV + c0);

  for (int g = 0; g < 16; ++g) {
    const int j0 = g*4;
    if (g < 15) {
      #pragma unroll
      for (int rr = 0; rr < 4; ++rr)
        xn[rr] = ntload4(srow + (size_t)(j0+4+rr)*HIDV + c0);
    }
    #pragma unroll
    for (int rr = 0; rr < 4; ++rr) {
      const int j = j0 + rr;
      f4 xx = x[rr];
      unsigned long long bal = __ballot(xx.x != 0.f || xx.y != 0.f ||
                                        xx.z != 0.f || xx.w != 0.f);
      if (bal) {
        cntf += 1.f;
        S1 += xx;
        S2 += xx*xx;
      }
      float sp0 = dotf4(qk0, xx);
      float sp1 = dotf4(qk1, xx);
      float sp2 = dotf4(qk2, xx);
      float sp3 = dotf4(qk3, xx);
      sp0 = red64f(sp0); sp1 = red64f(sp1);
      sp2 = red64f(sp2); sp3 = red64f(sp3);
      if (j < KR-1) {
        f4 u = xx * dw;
        ntstore4(urow + (size_t)(j+1)*HIDV + c0, u);
        float f = dw * 0.125f;
        float e0 = __expf(sp0*f), e1 = __expf(sp1*f);
        float e2 = __expf(sp2*f), e3 = __expf(sp3*f);
        se0 += e0; se1 += e1; se2 += e2; se3 += e3;
        pv0 += xx * (e0*dw); pv1 += xx * (e1*dw);
        pv2 += xx * (e2*dw); pv3 += xx * (e3*dw);
      }
      dw *= 0.95f;
    }
    if (g < 15) {
      #pragma unroll
      for (int rr = 0; rr < 4; ++rr) x[rr] = xn[rr];
    }
  }

  const float msum = cntf + 1e-8f;
  const float inv = 1.f / msum;
  f4 mn;
  mn.x = S1.x*inv; mn.y = S1.y*inv; mn.z = S1.z*inv; mn.w = S1.w*inv;
  *reinterpret_cast<f4*>(mean_ws + (size_t)b*HIDV + c0) = mn;

  float ind = 0.f;
  {
    float vx = S2.x - 2.f*mn.x*S1.x + mn.x*mn.x*cntf;
    float vy = S2.y - 2.f*mn.y*S1.y + mn.y*mn.y*cntf;
    float vz = S2.z - 2.f*mn.z*S1.z + mn.z*mn.z*cntf;
    float vw = S2.w - 2.f*mn.w*S1.w + mn.w*mn.w*cntf;
    float sx = sqrtf(fmaxf(vx,0.f)*inv), sy = sqrtf(fmaxf(vy,0.f)*inv);
    float sz = sqrtf(fmaxf(vz,0.f)*inv), sw = sqrtf(fmaxf(vw,0.f)*inv);
    ind += (fabsf((msgr.x-mn.x)/(sx+1e-8f)) > 2.f) ? 1.f : 0.f;
    ind += (fabsf((msgr.y-mn.y)/(sy+1e-8f)) > 2.f) ? 1.f : 0.f;
    ind += (fabsf((msgr.z-mn.z)/(sz+1e-8f)) > 2.f) ? 1.f : 0.f;
    ind += (fabsf((msgr.w-mn.w)/(sw+1e-8f)) > 2.f) ? 1.f : 0.f;
  }
  ind = red64f(ind);

  float* pvp = pv_ws + (size_t)b*(NH*HIDV);
  *reinterpret_cast<f4*>(pvp + 0*HIDV + c0) = pv0;
  *reinterpret_cast<f4*>(pvp + 1*HIDV + c0) = pv1;
  *reinterpret_cast<f4*>(pvp + 2*HIDV + c0) = pv2;
  *reinterpret_cast<f4*>(pvp + 3*HIDV + c0) = pv3;

  if (lane == 0) {
    se_ws[(size_t)b*NH + 0] = se0;
    se_ws[(size_t)b*NH + 1] = se1;
    se_ws[(size_t)b*NH + 2] = se2;
    se_ws[(size_t)b*NH + 3] = se3;
    stat_ws[b] = ind * (1.f/256.f);
  }
}

// ---------------- K3 (MFMA): im1/imp, row0, ctx = bv + a0*imp*Vm + inv*Vp, out proj ----------------
__global__ __launch_bounds__(256) void k3_mfma(
    const unsigned short* __restrict__ msgb, const float* __restrict__ msg,
    const float* __restrict__ mean_ws, const float* __restrict__ pv_ws,
    const float* __restrict__ se_ws, const float* __restrict__ s0c_ws,
    const float* __restrict__ stat_ws, const float* __restrict__ la_ws,
    const float* __restrict__ b_im1, const float* __restrict__ w_im2,
    const float* __restrict__ b_im2, const float* __restrict__ ipb,
    const float* __restrict__ opb,
    const unsigned short* __restrict__ IM1F, const unsigned short* __restrict__ WVF,
    const unsigned short* __restrict__ OPF,
    float* __restrict__ upd, float* __restrict__ agg, int B)
{
  __shared__ float ctx_lds[16][260];
  __shared__ float part[4][16];
  __shared__ float imp_s[16];
  __shared__ float a0i_s[16][NH];
  __shared__ float inv_s[16][NH];
  const int t = threadIdx.x, l = t & 63, w = t >> 6;
  const int lr = l & 15, lk = l >> 4;
  const int b0 = blockIdx.x * 16;

  const unsigned short* arow = msgb + (size_t)(b0 + lr) * HIDV;
  const float* meanrow = mean_ws + (size_t)(b0 + lr) * HIDV;

  // im1 GEMM: A = [msg | mean] (K=512), N: ntiles w*4+n
  f4 ga[4];
  #pragma unroll
  for (int n = 0; n < 4; ++n) {
    float bi = b_im1[w*64 + n*16 + lr];
    f4 v = {bi, bi, bi, bi};
    ga[n] = v;
  }
  #pragma unroll
  for (int s = 0; s < 16; ++s) {
    bh8 a;
    if (s < 8) {
      a = *reinterpret_cast<const bh8*>(arow + s*32 + lk*8);
    } else {
      int k0 = (s-8)*32 + lk*8;
      f4 lo = *reinterpret_cast<const f4*>(meanrow + k0);
      f4 hi = *reinterpret_cast<const f4*>(meanrow + k0 + 4);
      a = cvt8(lo, hi);
    }
    #pragma unroll
    for (int n = 0; n < 4; ++n) {
      bh8 bw = *reinterpret_cast<const bh8*>(IM1F + (((size_t)(w*4+n)*16 + s)*64 + l)*8);
      ga[n] = MFMA16(a, bw, ga[n]);
    }
  }
  // imp partial: relu(g)*w_im2, col-sum
  {
    float vv[4] = {0.f, 0.f, 0.f, 0.f};
    #pragma unroll
    for (int n = 0; n < 4; ++n) {
      float wi = w_im2[w*64 + n*16 + lr];
      #pragma unroll
      for (int qq = 0; qq < 4; ++qq)
        vv[qq] += fmaxf(ga[n][qq], 0.f) * wi;
    }
    #pragma unroll
    for (int m = 1; m < 16; m <<= 1) {
      #pragma unroll
      for (int qq = 0; qq < 4; ++qq) vv[qq] += __shfl_xor(vv[qq], m, 64);
    }
    if (lr == 0) {
      #pragma unroll
      for (int qq = 0; qq < 4; ++qq) part[w][lk*4+qq] = vv[qq];
    }
  }
  __syncthreads();
  if (t < 16) {
    float x = part[0][t]+part[1][t]+part[2][t]+part[3][t] + b_im2[0];
    float sp = fmaxf(x, 0.f) + log1pf(expf(-fabsf(x)));
    float an = 0.5f*stat_ws[b0+t] + 0.5f*la_ws[b0+t];
    imp_s[t] = sp * (1.f + an);
  }
  __syncthreads();

  // softmax-finish scalars per (row, head)
  if (t < 16*NH) {
    int r = t >> 2, h = t & 3;
    float impr = imp_s[r];
    float s0 = impr * s0c_ws[(size_t)(b0+r)*NH + h] * 0.125f;
    float e0 = __expf(s0);
    float invd = 1.f / (e0 + se_ws[(size_t)(b0+r)*NH + h]);
    a0i_s[r][h] = e0 * invd * impr;
    inv_s[r][h] = invd;
  }

  // Vm GEMM: A = msg (bf16 global)
  f4 vm[4], vp[4];
  #pragma unroll
  for (int n = 0; n < 4; ++n) { f4 z = {0.f,0.f,0.f,0.f}; vm[n] = z; vp[n] = z; }
  #pragma unroll
  for (int s = 0; s < 8; ++s) {
    bh8 a = *reinterpret_cast<const bh8*>(arow + s*32 + lk*8);
    #pragma unroll
    for (int n = 0; n < 4; ++n) {
      bh8 bw = *reinterpret_cast<const bh8*>(WVF + (((size_t)(w*4+n)*8 + s)*64 + l)*8);
      vm[n] = MFMA16(a, bw, vm[n]);
    }
  }
  // Vp GEMM: A = pv[b][head=w][*] (f32 global + cvt); wave w's cols == head w
  {
    const float* pvrow = pv_ws + (size_t)(b0 + lr)*(NH*HIDV) + w*HIDV;
    #pragma unroll
    for (int s = 0; s < 8; ++s) {
      int k0 = s*32 + lk*8;
      f4 lo = *reinterpret_cast<const f4*>(pvrow + k0);
      f4 hi = *reinterpret_cast<const f4*>(pvrow + k0 + 4);
      bh8 a = cvt8(lo, hi);
      #pragma unroll
      for (int n = 0; n < 4; ++n) {
        bh8 bw = *reinterpret_cast<const bh8*>(WVF + (((size_t)(w*4+n)*8 + s)*64 + l)*8);
        vp[n] = MFMA16(a, bw, vp[n]);
      }
    }
  }
  __syncthreads();   // imp_s/a0i_s/inv_s visible to all

  // upd row 0: msg * imp (exact fp32 msg)
  #pragma unroll
  for (int r = 0; r < 16; ++r)
    upd[(size_t)(b0+r)*KR*HIDV + t] = msg[(size_t)(b0+r)*HIDV + t] * imp_s[r];

  // combine -> ctx_lds
  #pragma unroll
  for (int n = 0; n < 4; ++n) {
    float bv = ipb[2*HIDV + w*64 + n*16 + lr];
    #pragma unroll
    for (int qq = 0; qq < 4; ++qq) {
      int row = lk*4 + qq;
      ctx_lds[row][w*64 + n*16 + lr] = bv + a0i_s[row][w]*vm[n][qq] + inv_s[row][w]*vp[n][qq];
    }
  }
  __syncthreads();

  // op GEMM: A = ctx (LDS f32 -> bf16), B = OPF
  {
    f4 ag[4];
    #pragma unroll
    for (int n = 0; n < 4; ++n) {
      float bo = opb[w*64 + n*16 + lr];
      f4 v = {bo, bo, bo, bo};
      ag[n] = v;
    }
    const float* crow = &ctx_lds[lr][0];
    #pragma unroll
    for (int s = 0; s < 8; ++s) {
      int k0 = s*32 + lk*8;
      f4 lo = *reinterpret_cast<const f4*>(crow + k0);
      f4 hi = *reinterpret_cast<const f4*>(crow + k0 + 4);
      bh8 a = cvt8(lo, hi);
      #pragma unroll
      for (int n = 0; n < 4; ++n) {
        bh8 bw = *reinterpret_cast<const bh8*>(OPF + (((size_t)(w*4+n)*8 + s)*64 + l)*8);
        ag[n] = MFMA16(a, bw, ag[n]);
      }
    }
    #pragma unroll
    for (int n = 0; n < 4; ++n)
      #pragma unroll
      for (int qq = 0; qq < 4; ++qq)
        agg[(size_t)(b0 + lk*4 + qq)*HIDV + w*64 + n*16 + lr] = ag[n][qq];
  }
}

extern "C" void kernel_launch(void* const* d_in, const int* in_sizes, int n_in,
                              void* d_out, int out_size, void* d_ws, size_t ws_size,
                              hipStream_t stream) {
  const float* storage = (const float*)d_in[0];
  const float* msg     = (const float*)d_in[1];
  const float* w_ad1   = (const float*)d_in[2];
  const float* b_ad1   = (const float*)d_in[3];
  const float* w_ad2   = (const float*)d_in[4];
  const float* b_ad2   = (const float*)d_in[5];
  const float* w_im1   = (const float*)d_in[6];
  const float* b_im1   = (const float*)d_in[7];
  const float* w_im2   = (const float*)d_in[8];
  const float* b_im2   = (const float*)d_in[9];
  const float* ipw     = (const float*)d_in[10];
  const float* ipb     = (const float*)d_in[11];
  const float* opw     = (const float*)d_in[12];
  const float* opb     = (const float*)d_in[13];

  const int B = in_sizes[1] / HIDV;
  float* upd = (float*)d_out;
  float* agg = upd + (size_t)B*KR*HIDV;

  float* wsf = (float*)d_ws;
  size_t off = 0;
  float* qk    = wsf + off; off += (size_t)B*NH*HIDV;
  float* pv1   = wsf + off; off += (size_t)B*NH*HIDV;
  float* mean  = wsf + off; off += (size_t)B*HIDV;
  float* se1   = wsf + off; off += (size_t)B*NH;
  float* s0c   = wsf + off; off += (size_t)B*NH;
  float* stat  = wsf + off; off += (size_t)B;
  float* la    = wsf + off; off += (size_t)B;
  unsigned short* usb = (unsigned short*)(wsf + off);
  size_t uo = 0;
  unsigned short* msgb = usb + uo; uo += (size_t)B*HIDV;
  unsigned short* WQF  = usb + uo; uo += 65536;
  unsigned short* WKF  = usb + uo; uo += 65536;
  unsigned short* AD1F = usb + uo; uo += 32768;
  unsigned short* IM1F = usb + uo; uo += 131072;
  unsigned short* WVF  = usb + uo; uo += 65536;
  unsigned short* OPF  = usb + uo; uo += 65536;

  hipLaunchKernelGGL(k_prep_w, dim3(208), dim3(256), 0, stream,
                     ipw, w_ad1, w_im1, opw, WQF, WKF, AD1F, IM1F, WVF, OPF);
  hipLaunchKernelGGL(k_prep_msg, dim3((B*HIDV/8 + 255)/256), dim3(256), 0, stream,
                     msg, msgb, B*HIDV/8);
  hipLaunchKernelGGL(k0_mfma, dim3(B/16), dim3(256), 0, stream,
                     msgb, ipb, b_ad1, w_ad2, b_ad2, WQF, WKF, AD1F, qk, la, B);
  hipLaunchKernelGGL(k1_stream, dim3((B+3)/4), dim3(256), 0, stream,
                     storage, msg, qk, upd, mean, pv1, se1, s0c, stat, B);
  hipLaunchKernelGGL(k3_mfma, dim3(B/16), dim3(256), 0, stream,
                     msgb, msg, mean, pv1, se1, s0c, stat, la,
                     b_im1, w_im2, b_im2, ipb, opb,
                     IM1F, WVF, OPF, upd, agg, B);
}